// Round 1
// baseline (5962.547 us; speedup 1.0000x reference)
//
#include <hip/hip_runtime.h>
#include <hip/hip_bf16.h>

// Problem constants (from reference)
#define BB 32
#define LL 8192
#define CC 64          // C_OUT; C_IN = CC+1 (t channel)
#define KW 3
#define TILE_L 32
#define THREADS 256

using bf16 = __hip_bfloat16;

__device__ __forceinline__ float4 ld4g(const float* p) {
    return *reinterpret_cast<const float4*>(p);
}
__device__ __forceinline__ float4 ld4g(const bf16* p) {
    uint2 r = *reinterpret_cast<const uint2*>(p);
    float4 o;
    o.x = __uint_as_float(r.x << 16);
    o.y = __uint_as_float(r.x & 0xffff0000u);
    o.z = __uint_as_float(r.y << 16);
    o.w = __uint_as_float(r.y & 0xffff0000u);
    return o;
}
__device__ __forceinline__ unsigned short f2bf(float f) {
    bf16 h = __float2bfloat16(f);
    return *reinterpret_cast<unsigned short*>(&h);
}
__device__ __forceinline__ void st4g(float* p, float4 v) {
    *reinterpret_cast<float4*>(p) = v;
}
__device__ __forceinline__ void st4g(bf16* p, float4 v) {
    uint2 r;
    r.x = (unsigned)f2bf(v.x) | ((unsigned)f2bf(v.y) << 16);
    r.y = (unsigned)f2bf(v.z) | ((unsigned)f2bf(v.w) << 16);
    *reinterpret_cast<uint2*>(p) = r;
}

// One ODE-func eval fused with RK4 AXPYs.
// k = relu(conv(concat(u_in, t)) + bias)
// MODE 0: acc = y0 + c_acc*k; u_out = y0 + c_u*k      (eval 1; y0 == u_in)
// MODE 1: acc += c_acc*k;      u_out = y0 + c_u*k     (evals 2,3)
// MODE 2: acc += c_acc*k                              (eval 4)
template <typename TIN, typename TOUT, int MODE>
__launch_bounds__(THREADS)
__global__ void eval_kernel(const TIN* __restrict__ u_in, const float* __restrict__ y0,
                            float* __restrict__ acc, TOUT* __restrict__ u_out,
                            const float* __restrict__ w, const float* __restrict__ bias,
                            float t, float c_acc, float c_u) {
    // z tile: rows 0..TILE_L+1 map to l = l0-1+row; row stride 66 (64 + 2 pad)
    __shared__ float zs[(TILE_L + 2) * 66];
    // w (y-part) relayout: [kw][ci/2][co][2]  -> b64 reads, conflict-free
    __shared__ float wsy[KW * 32 * CC * 2];
    __shared__ float wts[KW][CC];   // t-channel weights w[kw][64][co]
    __shared__ float bs[CC];

    const int tid = threadIdx.x;
    const int b = blockIdx.y;
    const int l0 = blockIdx.x * TILE_L;

    // ---- stage w into LDS ----
    for (int idx = tid; idx < KW * CC * CC; idx += THREADS) {
        int co = idx & 63;
        int ci = (idx >> 6) & 63;
        int kw = idx >> 12;
        float v = w[kw * ((CC + 1) * CC) + ci * CC + co];
        wsy[((kw * 32 + (ci >> 1)) * CC + co) * 2 + (ci & 1)] = v;
    }
    if (tid < KW * CC) {
        int kw = tid >> 6, co = tid & 63;
        wts[kw][co] = w[kw * ((CC + 1) * CC) + CC * CC + co];
    }
    if (tid < CC) bs[tid] = bias[tid];

    // ---- stage z tile (with halo, zero-padded at sequence ends) ----
    for (int idx = tid; idx < (TILE_L + 2) * (CC / 4); idx += THREADS) {
        int row = idx >> 4;
        int c4 = (idx & 15) * 4;
        int l = l0 - 1 + row;
        float4 v;
        if (l >= 0 && l < LL) v = ld4g(u_in + ((size_t)b * LL + l) * CC + c4);
        else                  v = make_float4(0.f, 0.f, 0.f, 0.f);
        float* zp = &zs[row * 66 + c4];
        zp[0] = v.x; zp[1] = v.y; zp[2] = v.z; zp[3] = v.w;
    }
    __syncthreads();

    const int pt = tid & 15;        // position within 16-group (fast dim: conflict-free z reads)
    const int co_t = tid >> 4;      // 0..15 -> 4 consecutive channels each
    const int co4 = co_t * 4;

    float k[2][4];
#pragma unroll
    for (int j = 0; j < 2; j++)
#pragma unroll
        for (int i = 0; i < 4; i++) k[j][i] = 0.f;

#pragma unroll
    for (int kw = 0; kw < KW; kw++) {
#pragma unroll 8
        for (int cb = 0; cb < 32; cb++) {
            const float* wp = &wsy[((kw * 32 + cb) * CC + co4) * 2];
            float2 wv0 = *(const float2*)(wp + 0);
            float2 wv1 = *(const float2*)(wp + 2);
            float2 wv2 = *(const float2*)(wp + 4);
            float2 wv3 = *(const float2*)(wp + 6);
#pragma unroll
            for (int j = 0; j < 2; j++) {
                float2 zv = *(const float2*)&zs[(pt + 16 * j + kw) * 66 + cb * 2];
                k[j][0] += zv.x * wv0.x + zv.y * wv0.y;
                k[j][1] += zv.x * wv1.x + zv.y * wv1.y;
                k[j][2] += zv.x * wv2.x + zv.y * wv2.y;
                k[j][3] += zv.x * wv3.x + zv.y * wv3.y;
            }
        }
    }

    // ---- epilogue: t-channel + bias + relu, then RK4 AXPYs ----
#pragma unroll
    for (int j = 0; j < 2; j++) {
        int l = l0 + pt + 16 * j;
        float4 kk;
#pragma unroll
        for (int i = 0; i < 4; i++) {
            int co = co4 + i;
            float wtsum = wts[1][co];
            if (l > 0) wtsum += wts[0][co];          // kw=0 tap padded at l==0
            if (l < LL - 1) wtsum += wts[2][co];     // kw=2 tap padded at l==L-1
            float v = k[j][i] + t * wtsum + bs[co];
            (&kk.x)[i] = fmaxf(v, 0.f);
        }
        size_t base = ((size_t)b * LL + l) * CC + co4;
        float4 yv;
        if (MODE < 2) yv = ld4g(y0 + base);
        float4 av;
        if (MODE == 0) {
            float4 y2 = ld4g(y0 + base);
            av.x = y2.x + c_acc * kk.x; av.y = y2.y + c_acc * kk.y;
            av.z = y2.z + c_acc * kk.z; av.w = y2.w + c_acc * kk.w;
        } else {
            av = *(const float4*)(acc + base);
            av.x += c_acc * kk.x; av.y += c_acc * kk.y;
            av.z += c_acc * kk.z; av.w += c_acc * kk.w;
        }
        *(float4*)(acc + base) = av;
        if (MODE < 2) {
            float4 uv;
            uv.x = yv.x + c_u * kk.x; uv.y = yv.y + c_u * kk.y;
            uv.z = yv.z + c_u * kk.z; uv.w = yv.w + c_u * kk.w;
            st4g(u_out + base, uv);
        }
    }
}

template <typename UT>
static void run_steps(const float* x, const float* w, const float* bias, float* out,
                      UT* Ua, UT* Ub, float* P0, hipStream_t stream) {
    const float h = 1.0f / 8.0f;
    dim3 grid(LL / TILE_L, BB), block(THREADS);
    for (int s = 0; s < 8; s++) {
        float t0 = s * h;
        const float* Y = (s == 0) ? x : ((s & 1) ? P0 : out);
        float* ACC = (s & 1) ? out : P0;
        eval_kernel<float, UT, 0><<<grid, block, 0, stream>>>(
            Y, Y, ACC, Ua, w, bias, t0, h / 6.f, 0.5f * h);
        eval_kernel<UT, UT, 1><<<grid, block, 0, stream>>>(
            Ua, Y, ACC, Ub, w, bias, t0 + 0.5f * h, h / 3.f, 0.5f * h);
        eval_kernel<UT, UT, 1><<<grid, block, 0, stream>>>(
            Ub, Y, ACC, Ua, w, bias, t0 + 0.5f * h, h / 3.f, h);
        eval_kernel<UT, float, 2><<<grid, block, 0, stream>>>(
            Ua, Y, ACC, (float*)nullptr, w, bias, t0 + h, h / 6.f, 0.f);
    }
}

extern "C" void kernel_launch(void* const* d_in, const int* in_sizes, int n_in,
                              void* d_out, int out_size, void* d_ws, size_t ws_size,
                              hipStream_t stream) {
    const float* x = (const float*)d_in[0];
    const float* w = (const float*)d_in[1];
    const float* bias = (const float*)d_in[2];
    float* out = (float*)d_out;
    const size_t S = (size_t)BB * LL * CC;

    if (ws_size >= 3 * S * sizeof(float)) {
        // fp32 eval-state scratch: Ua, Ub, P0
        float* Ua = (float*)d_ws;
        float* Ub = Ua + S;
        float* P0 = Ub + S;
        run_steps<float>(x, w, bias, out, Ua, Ub, P0, stream);
    } else {
        // tighter ws: bf16 eval-state scratch (well within the 0.153 absmax threshold)
        bf16* Ua = (bf16*)d_ws;
        bf16* Ub = Ua + S;
        float* P0 = (float*)((char*)d_ws + 2 * S * sizeof(bf16));
        run_steps<bf16>(x, w, bias, out, Ua, Ub, P0, stream);
    }
}

// Round 2
// 700.712 us; speedup vs baseline: 8.5093x; 8.5093x over previous
//
#include <hip/hip_runtime.h>
#include <hip/hip_bf16.h>

// ODEBlock1D: RK4 over relu(conv1d_k3(concat(y,t)) + b), B=32 L=8192 C=64, 8 steps.
// One kernel per RK4 step: all 4 evals fused in LDS, conv via bf16 MFMA with
// split-weight (hi+lo) for fp32-grade weight precision.

#define BB 32
#define LL 8192
#define CC 64
#define TILE 64          // output positions per block
#define NROW 80          // compute rows r=1..80  (l = l0-9+r)
#define BUFR 82          // + zero pad rows r=0,81
#define ZST 72           // bf16 row stride (64+8 pad) -> 144B rows, 16B aligned
#define YST 66           // fp32 row stride for ys
#define CENT_LO 9        // r of l0
#define CENT_HI 72       // r of l0+63
#define THREADS 256

typedef __attribute__((ext_vector_type(8))) short bf16x8;
typedef __attribute__((ext_vector_type(4))) float f32x4;

__device__ __forceinline__ unsigned short f2bf_u(float f) {
    __hip_bfloat16 h = __float2bfloat16(f);
    return *reinterpret_cast<unsigned short*>(&h);
}

__launch_bounds__(THREADS, 3)
__global__ void step_kernel(const float* __restrict__ y_in, float* __restrict__ y_out,
                            const float* __restrict__ w, const float* __restrict__ bias,
                            float t0, float h)
{
    __shared__ float ys[BUFR * YST];            // fp32 y tile (AXPY base)
    __shared__ unsigned short zA[BUFR * ZST];   // bf16 conv-input ping
    __shared__ unsigned short zB[BUFR * ZST];   // bf16 conv-input pong
    __shared__ float wts[3 * CC];               // t-channel weights
    __shared__ float bs[CC];

    const int tid = threadIdx.x;
    const int b = blockIdx.y;
    const int l0 = blockIdx.x * TILE;
    const int lane = tid & 63;
    const int wv = tid >> 6;        // 4 waves -> co tiles of 16
    const int co0 = wv * 16;
    const int g = lane >> 4;        // quad id 0..3
    const int ml = lane & 15;

    // ---- B fragments: w split into hi+lo bf16 (fp32-accurate weights) ----
    // k-chunk c: kw=c>>1, ci = (c&1)*32 + k32;  lane holds k32=g*8+j, n=ml
    bf16x8 bhi[6], blo[6];
#pragma unroll
    for (int c = 0; c < 6; c++) {
        const int kw = c >> 1;
        const int cbase = (c & 1) * 32 + g * 8;
        const float* wp = w + kw * (65 * CC) + cbase * CC + co0 + ml;
#pragma unroll
        for (int j = 0; j < 8; j++) {
            float v = wp[j * CC];
            unsigned short hi = f2bf_u(v);
            float vhi = __uint_as_float(((unsigned)hi) << 16);
            unsigned short lo = f2bf_u(v - vhi);
            bhi[c][j] = (short)hi;
            blo[c][j] = (short)lo;
        }
    }

    if (tid < 3 * CC) wts[tid] = w[(tid >> 6) * (65 * CC) + CC * CC + (tid & 63)];
    if (tid < CC) bs[tid] = bias[tid];

    // zero the conv-pad rows of both z buffers (never written again)
    if (tid < CC) {
        zA[0 * ZST + tid] = 0; zA[81 * ZST + tid] = 0;
        zB[0 * ZST + tid] = 0; zB[81 * ZST + tid] = 0;
    }

    // ---- stage y tile rows 1..80 (l = l0-9+r), zero outside [0,L) ----
    for (int idx = tid; idx < NROW * 16; idx += THREADS) {
        int r = 1 + (idx >> 4);
        int c4 = (idx & 15) * 4;
        int l = l0 - 9 + r;
        float4 v = make_float4(0.f, 0.f, 0.f, 0.f);
        if (l >= 0 && l < LL)
            v = *reinterpret_cast<const float4*>(y_in + ((size_t)b * LL + l) * CC + c4);
        float* yp = &ys[r * YST + c4];
        yp[0] = v.x; yp[1] = v.y; yp[2] = v.z; yp[3] = v.w;
        unsigned short* zp = &zA[r * ZST + c4];
        zp[0] = f2bf_u(v.x); zp[1] = f2bf_u(v.y);
        zp[2] = f2bf_u(v.z); zp[3] = f2bf_u(v.w);
    }
    __syncthreads();

    // RK4 coefficients
    const float ca0 = h / 6.f, ca1 = h / 3.f;
    const int co = co0 + ml;
    const float w1t = wts[CC + co], w0t = wts[co], w2t = wts[2 * CC + co];
    const float bv = bs[co];

    // per-lane accumulator (y + sum of coeff*k), same (row,co) mapping every eval
    float accR[5][4];

#pragma unroll 1
    for (int e = 0; e < 4; e++) {
        const unsigned short* zin = (e & 1) ? zB : zA;
        unsigned short* zout = (e & 1) ? zA : zB;
        const float t = t0 + ((e == 0) ? 0.f : (e == 3) ? h : 0.5f * h);
        const float cacc = (e == 0 || e == 3) ? ca0 : ca1;
        const float cuu = (e == 2) ? h : 0.5f * h;

#pragma unroll
        for (int m = 0; m < 5; m++) {
            const int r0 = 1 + 16 * m;
            f32x4 acc = {0.f, 0.f, 0.f, 0.f};
#pragma unroll
            for (int c = 0; c < 6; c++) {
                const int kw = c >> 1;
                const int zoff = (c & 1) * 32 + g * 8;
                const int row = r0 + ml + kw - 1;
                const bf16x8 a =
                    *reinterpret_cast<const bf16x8*>(&zin[row * ZST + zoff]);
                acc = __builtin_amdgcn_mfma_f32_16x16x32_bf16(a, bhi[c], acc, 0, 0, 0);
                acc = __builtin_amdgcn_mfma_f32_16x16x32_bf16(a, blo[c], acc, 0, 0, 0);
            }
            // epilogue: t-channel + bias + relu, then RK4 AXPYs
#pragma unroll
            for (int i = 0; i < 4; i++) {
                const int rr = r0 + g * 4 + i;
                const int l = l0 - 9 + rr;
                float wt = w1t;
                if (l > 0) wt += w0t;
                if (l < LL - 1) wt += w2t;
                float k = fmaxf(acc[i] + t * wt + bv, 0.f);
                const float yv = ys[rr * YST + co];
                if (e < 3) {
                    float u = yv + cuu * k;
                    if (l < 0 || l >= LL) u = 0.f;   // keep seq-boundary zero padding
                    zout[rr * ZST + co] = f2bf_u(u);
                }
                accR[m][i] = ((e == 0) ? yv : accR[m][i]) + cacc * k;
            }
        }
        __syncthreads();
    }

    // ---- store central rows (l0..l0+63) from registers ----
#pragma unroll
    for (int m = 0; m < 5; m++) {
#pragma unroll
        for (int i = 0; i < 4; i++) {
            const int rr = 1 + 16 * m + g * 4 + i;
            if (rr >= CENT_LO && rr <= CENT_HI) {
                const int l = l0 - 9 + rr;
                y_out[((size_t)b * LL + l) * CC + co] = accR[m][i];
            }
        }
    }
}

extern "C" void kernel_launch(void* const* d_in, const int* in_sizes, int n_in,
                              void* d_out, int out_size, void* d_ws, size_t ws_size,
                              hipStream_t stream) {
    const float* x = (const float*)d_in[0];
    const float* w = (const float*)d_in[1];
    const float* bias = (const float*)d_in[2];
    float* out = (float*)d_out;
    float* P0 = (float*)d_ws;   // needs 32*8192*64*4 = 67.1 MB scratch
    const float h = 1.0f / 8.0f;

    dim3 grid(LL / TILE, BB), block(THREADS);
    for (int s = 0; s < 8; s++) {
        const float* yin = (s == 0) ? x : ((s & 1) ? P0 : out);
        float* yout = (s & 1) ? out : P0;   // step 7 writes `out`
        step_kernel<<<grid, block, 0, stream>>>(yin, yout, w, bias, s * h, h);
    }
}